// Round 8
// baseline (338.757 us; speedup 1.0000x reference)
//
#include <hip/hip_runtime.h>
#include <hip/hip_bf16.h>

typedef __attribute__((ext_vector_type(8))) short bf16x8;
typedef __attribute__((ext_vector_type(4))) float f32x4;
typedef __attribute__((ext_vector_type(2))) float f32x2;

#define EPB 4096         // edges per partition block
#define BUCKET_BITS 8
#define BUCKET_SIZE 256  // nodes per bucket
#define MAXBUCK 512

static __device__ __forceinline__ unsigned short f2bf(float f) {
    union { float f; unsigned u; } v; v.f = f;
    unsigned r = v.u + 0x7FFF + ((v.u >> 16) & 1);
    return (unsigned short)(r >> 16);
}
static __device__ __forceinline__ float asf(unsigned u) {
    union { unsigned u; float f; } v; v.u = u;
    return v.f;
}
// packed bf16 pair -> f32x2 {lo, hi}
static __device__ __forceinline__ f32x2 cvt2(unsigned u) {
    f32x2 r;
    r.x = asf(u << 16);
    r.y = asf(u & 0xFFFF0000u);
    return r;
}

// ================= K1: prep — weight swizzles + per-chunk bucket counts (merged) =================
// Counting branch: LDS histogram per chunk -> one global atomicAdd per nonzero bucket.
// Replaces the 391x391 hist matrix + bucket_total kernel.
__global__ __launch_bounds__(256) void prep(const float* __restrict__ Wrel1,
                                            const float* __restrict__ Wroot1,
                                            const float* __restrict__ Wrel2,
                                            const float* __restrict__ Wroot2,
                                            const float* __restrict__ Wlin,
                                            const int* __restrict__ dst,
                                            unsigned short* __restrict__ bsw1,
                                            unsigned short* __restrict__ bsw2,
                                            unsigned short* __restrict__ bswL,
                                            int* __restrict__ bucketTot,
                                            int E, int nblk, int nbuck) {
    __shared__ int h[MAXBUCK];
    int blk = blockIdx.x, t = threadIdx.x;
    if (blk < 256) {
        const float* Wrel  = (blk < 128) ? Wrel1 : Wrel2;
        const float* Wroot = (blk < 128) ? Wroot1 : Wroot2;
        unsigned short* bsw = (blk < 128) ? bsw1 : bsw2;
        int idx = (blk & 127) * 256 + t;  // 32768 total
        int j = idx & 7, L = (idx >> 3) & 63, ct = (idx >> 9) & 15, kt = idx >> 13;
        int k = kt * 32 + ((L >> 4) * 8) + j;
        int c = ct * 16 + (L & 15);
        float v = (c < 128) ? Wrel[k * 128 + c] : Wroot[k * 128 + (c - 128)];
        bsw[idx] = f2bf(v);
    } else if (blk < 304) {
        int idx = (blk - 256) * 256 + t;  // 12288 total
        int tt = idx;
        int j = tt & 7; tt >>= 3;
        int L = tt & 63; tt >>= 6;
        int ct = tt % 3;
        int kt = tt / 3;
        int k = kt * 32 + ((L >> 4) * 8) + j;
        int c = ct * 16 + (L & 15);
        float v = (c < 40) ? Wlin[k * 40 + c] : 0.f;
        bswL[idx] = f2bf(v);
    } else {
        int hb = blk - 304;
        for (int i = t; i < MAXBUCK; i += 256) h[i] = 0;
        __syncthreads();
        int e0 = hb * EPB;
#pragma unroll
        for (int it = 0; it < EPB / 256; it++) {
            int e = e0 + it * 256 + t;
            if (e < E) atomicAdd(&h[dst[e] >> BUCKET_BITS], 1);
        }
        __syncthreads();
        for (int i = t; i < nbuck; i += 256) {
            int c = h[i];
            if (c) atomicAdd(&bucketTot[i], c);
        }
    }
}

// ================= K2: exclusive scan of bucket totals (pair-scan, nbuck <= 512) =================
__global__ __launch_bounds__(256) void bucket_scan(const int* __restrict__ total,
                                                   int* __restrict__ base, int nbuck) {
    __shared__ int s[256];
    int t = threadIdx.x;
    int e0 = (2 * t < nbuck) ? total[2 * t] : 0;
    int e1 = (2 * t + 1 < nbuck) ? total[2 * t + 1] : 0;
    int ps = e0 + e1;
    s[t] = ps; __syncthreads();
#pragma unroll
    for (int o = 1; o < 256; o <<= 1) {
        int x = (t >= o) ? s[t - o] : 0;
        __syncthreads();
        s[t] += x; __syncthreads();
    }
    int pbase = s[t] - ps;
    if (2 * t <= nbuck) base[2 * t] = pbase;
    if (2 * t + 1 <= nbuck) base[2 * t + 1] = pbase + e0;
}

// ================= K3: per-chunk LDS counting sort -> bucket-sorted packed records =================
// Slot ranges claimed via global atomicAdd on bucketCur (order within bucket is
// non-deterministic — downstream csrfin re-sorts and agg is an order-insensitive sum).
__global__ __launch_bounds__(256) void edge_part(const int* __restrict__ src,
                                                 const int* __restrict__ dst,
                                                 const int* __restrict__ bucketBase,
                                                 int* __restrict__ bucketCur,
                                                 int* __restrict__ part,
                                                 int E, int nblk, int nbuck) {
    __shared__ int hcnt[MAXBUCK];
    __shared__ int lstart[MAXBUCK];
    __shared__ int cur[MAXBUCK];
    __shared__ int gbase[MAXBUCK];
    __shared__ int s2[256];
    __shared__ int sdst[EPB];  // 16 KB
    __shared__ int ssrc[EPB];  // 16 KB
    int t = threadIdx.x, blk = blockIdx.x;
    int e0 = blk * EPB;
    int cnt = E - e0; if (cnt > EPB) cnt = EPB;
    for (int i = t; i < MAXBUCK; i += 256) hcnt[i] = 0;
    __syncthreads();
    int myd[EPB / 256], mys[EPB / 256];
#pragma unroll
    for (int it = 0; it < EPB / 256; it++) {
        int i = it * 256 + t;
        if (i < cnt) {
            myd[it] = dst[e0 + i];
            mys[it] = src[e0 + i];
            atomicAdd(&hcnt[myd[it] >> BUCKET_BITS], 1);
        }
    }
    __syncthreads();
    // claim global ranges for this chunk's buckets
    for (int i = t; i < nbuck; i += 256) {
        int c = hcnt[i];
        gbase[i] = c ? (bucketBase[i] + atomicAdd(&bucketCur[i], c)) : 0;
    }
    // local exclusive scan of bucket counts
    int p0 = hcnt[2 * t], p1 = hcnt[2 * t + 1];
    int ps = p0 + p1;
    s2[t] = ps; __syncthreads();
#pragma unroll
    for (int o = 1; o < 256; o <<= 1) {
        int x = (t >= o) ? s2[t - o] : 0;
        __syncthreads();
        s2[t] += x; __syncthreads();
    }
    int pbase = s2[t] - ps;
    lstart[2 * t] = pbase; lstart[2 * t + 1] = pbase + p0;
    cur[2 * t] = 0; cur[2 * t + 1] = 0;
    __syncthreads();
#pragma unroll
    for (int it = 0; it < EPB / 256; it++) {
        int i = it * 256 + t;
        if (i < cnt) {
            int b = myd[it] >> BUCKET_BITS;
            int p = lstart[b] + atomicAdd(&cur[b], 1);
            sdst[p] = myd[it];
            ssrc[p] = mys[it];
        }
    }
    __syncthreads();
    for (int i = t; i < cnt; i += 256) {
        int d = sdst[i], s = ssrc[i];
        int b = d >> BUCKET_BITS;
        part[gbase[b] + (i - lstart[b])] = ((d & (BUCKET_SIZE - 1)) << 17) | s;
    }
}

// ================= K4: csr_finalize (blocks 0..nbuck-1) + layer-1 GEMM (rest), merged =================
// GEMM branch stages B in LDS (64 KB): kills the 400 MB L2->L1 B re-read.
__global__ __launch_bounds__(256) void csrfin_gemm1(const int* __restrict__ part,
                                                    const int* __restrict__ bucketBase,
                                                    int* __restrict__ off_,
                                                    int* __restrict__ deg_,
                                                    int* __restrict__ csr_src,
                                                    const float* __restrict__ x,
                                                    const unsigned short* __restrict__ Bsw,
                                                    const float* __restrict__ bias,
                                                    unsigned short* __restrict__ xr,
                                                    unsigned short* __restrict__ accbf,
                                                    int N, int nbuck) {
    __shared__ unsigned short Bs[32768];  // 64 KB (GEMM branch)
    __shared__ int cur[BUCKET_SIZE];
    __shared__ int h[BUCKET_SIZE];
    __shared__ int tsum[256];
    int t = threadIdx.x;
    if (blockIdx.x < (unsigned)nbuck) {
        int b = blockIdx.x;
        int lo = bucketBase[b], hi = bucketBase[b + 1];
        int n0 = b * BUCKET_SIZE;
        h[t] = 0;
        __syncthreads();
        for (int i = lo + t; i < hi; i += 256) atomicAdd(&h[part[i] >> 17], 1);
        __syncthreads();
        int hv = h[t];
        tsum[t] = hv;
        __syncthreads();
#pragma unroll
        for (int o = 1; o < 256; o <<= 1) {
            int xx = (t >= o) ? tsum[t - o] : 0;
            __syncthreads();
            tsum[t] += xx;
            __syncthreads();
        }
        int st = tsum[t] - hv;
        cur[t] = st;
        int node = n0 + t;
        if (node < N) { off_[node] = lo + st; deg_[node] = hv; }
        __syncthreads();
        for (int i = lo + t; i < hi; i += 256) {
            int rec = part[i];
            int p = atomicAdd(&cur[rec >> 17], 1);
            csr_src[lo + p] = rec & 0x1FFFF;
        }
    } else {
        // stage B into LDS (block-uniform branch -> __syncthreads is safe)
        {
            uint4* d4 = (uint4*)Bs;
            const uint4* s4 = (const uint4*)Bsw;
#pragma unroll
            for (int i = 0; i < 16; i++) d4[t + i * 256] = s4[t + i * 256];
        }
        __syncthreads();
        int wid = (blockIdx.x - nbuck) * 4 + (t >> 6);
        int L = t & 63;
        int r0 = wid * 16;
        if (r0 >= N) return;
        int arow = r0 + (L & 15);
        f32x4 acc[16];
#pragma unroll
        for (int i = 0; i < 16; i++) acc[i] = (f32x4){0.f, 0.f, 0.f, 0.f};
#pragma unroll
        for (int kt = 0; kt < 4; kt++) {
            const float* Arow = x + (size_t)arow * 128 + ((L >> 4) * 8) + kt * 32;
            float4 a0 = *(const float4*)Arow;
            float4 a1 = *(const float4*)(Arow + 4);
            bf16x8 a;
            a[0] = (short)f2bf(a0.x); a[1] = (short)f2bf(a0.y);
            a[2] = (short)f2bf(a0.z); a[3] = (short)f2bf(a0.w);
            a[4] = (short)f2bf(a1.x); a[5] = (short)f2bf(a1.y);
            a[6] = (short)f2bf(a1.z); a[7] = (short)f2bf(a1.w);
#pragma unroll
            for (int ct = 0; ct < 16; ct++) {
                bf16x8 b = *(const bf16x8*)(Bs + (((kt * 16 + ct) * 64) + L) * 8);
                acc[ct] = __builtin_amdgcn_mfma_f32_16x16x32_bf16(a, b, acc[ct], 0, 0, 0);
            }
        }
        int rbase = r0 + (L >> 4) * 4;
        int cl = L & 15;
#pragma unroll
        for (int ct = 0; ct < 16; ct++) {
            int col = ct * 16 + cl;
#pragma unroll
            for (int r = 0; r < 4; r++) {
                int row = rbase + r;
                float v = acc[ct][r];
                if (col < 128)
                    xr[(size_t)row * 128 + col] = f2bf(v);
                else
                    accbf[(size_t)row * 128 + (col - 128)] = f2bf(v + bias[col - 128]);
            }
        }
    }
}

// ================= layer-2 GEMM (bf16 A, B staged in LDS, grid-stride tiles) =================
__global__ __launch_bounds__(256) void gemm_layer2(const unsigned short* __restrict__ Abf,
                                                   const unsigned short* __restrict__ Bsw,
                                                   const float* __restrict__ bias,
                                                   unsigned short* __restrict__ xr,
                                                   unsigned short* __restrict__ accbf, int N) {
    __shared__ unsigned short Bs[32768];  // 64 KB
    int t = threadIdx.x;
    {
        uint4* d4 = (uint4*)Bs;
        const uint4* s4 = (const uint4*)Bsw;
#pragma unroll
        for (int i = 0; i < 16; i++) d4[t + i * 256] = s4[t + i * 256];
    }
    __syncthreads();
    int w = t >> 6, L = t & 63;
    int nTiles = (N + 15) / 16;
    for (int tile = blockIdx.x * 4 + w; tile < nTiles; tile += gridDim.x * 4) {
        int r0 = tile * 16;
        int arow = r0 + (L & 15);
        f32x4 acc[16];
#pragma unroll
        for (int i = 0; i < 16; i++) acc[i] = (f32x4){0.f, 0.f, 0.f, 0.f};
#pragma unroll
        for (int kt = 0; kt < 4; kt++) {
            bf16x8 a = *((const bf16x8*)(Abf + (size_t)arow * 128 + ((L >> 4) * 8) + kt * 32));
#pragma unroll
            for (int ct = 0; ct < 16; ct++) {
                bf16x8 b = *(const bf16x8*)(Bs + (((kt * 16 + ct) * 64) + L) * 8);
                acc[ct] = __builtin_amdgcn_mfma_f32_16x16x32_bf16(a, b, acc[ct], 0, 0, 0);
            }
        }
        int rbase = r0 + (L >> 4) * 4;
        int cl = L & 15;
#pragma unroll
        for (int ct = 0; ct < 16; ct++) {
            int col = ct * 16 + cl;
#pragma unroll
            for (int r = 0; r < 4; r++) {
                int row = rbase + r;
                float v = acc[ct][r];
                if (col < 128)
                    xr[(size_t)row * 128 + col] = f2bf(v);
                else
                    accbf[(size_t)row * 128 + (col - 128)] = f2bf(v + bias[col - 128]);
            }
        }
    }
}

// ================= gather-aggregate + relu + bf16 convert (R0 structure, verbatim) =================
// one wave per node; 4 edges per dwordx4 load; f32x2 accumulators -> v_pk_add_f32
__global__ __launch_bounds__(256) void agg_relu_cvt(const unsigned short* __restrict__ xr,
                                                    const unsigned short* __restrict__ accbf,
                                                    const int* __restrict__ off_,
                                                    const int* __restrict__ deg,
                                                    const int* __restrict__ csr_src,
                                                    unsigned short* __restrict__ out, int N) {
    int node = blockIdx.x * 4 + (threadIdx.x >> 6);
    if (node >= N) return;
    int L = threadIdx.x & 63;
    int g = L >> 4;
    int f = L & 15;
    int o = off_[node];
    int d = deg[node];
    uint4 arow = (uint4){0, 0, 0, 0};
    if (g == 0) arow = *(const uint4*)(accbf + (size_t)node * 128 + f * 8);

    const int* ip = csr_src + o + g;
    const unsigned short* xrf = xr + f * 8;

    f32x2 a0 = (f32x2){0.f, 0.f}, a1 = (f32x2){0.f, 0.f};
    f32x2 a2 = (f32x2){0.f, 0.f}, a3 = (f32x2){0.f, 0.f};

    int d4 = d & ~3;
#pragma unroll 4
    for (int k = 0; k < d4; k += 4) {
        int s = ip[k];  // group-uniform (16 lanes same addr -> broadcast)
        uint4 p = *(const uint4*)(xrf + (size_t)s * 128);
        a0 += cvt2(p.x);
        a1 += cvt2(p.y);
        a2 += cvt2(p.z);
        a3 += cvt2(p.w);
    }
    if (d4 + g < d) {
        int s = ip[d4];
        uint4 p = *(const uint4*)(xrf + (size_t)s * 128);
        a0 += cvt2(p.x);
        a1 += cvt2(p.y);
        a2 += cvt2(p.z);
        a3 += cvt2(p.w);
    }
    a0.x += __shfl_xor(a0.x, 16, 64); a0.y += __shfl_xor(a0.y, 16, 64);
    a1.x += __shfl_xor(a1.x, 16, 64); a1.y += __shfl_xor(a1.y, 16, 64);
    a2.x += __shfl_xor(a2.x, 16, 64); a2.y += __shfl_xor(a2.y, 16, 64);
    a3.x += __shfl_xor(a3.x, 16, 64); a3.y += __shfl_xor(a3.y, 16, 64);
    a0.x += __shfl_xor(a0.x, 32, 64); a0.y += __shfl_xor(a0.y, 32, 64);
    a1.x += __shfl_xor(a1.x, 32, 64); a1.y += __shfl_xor(a1.y, 32, 64);
    a2.x += __shfl_xor(a2.x, 32, 64); a2.y += __shfl_xor(a2.y, 32, 64);
    a3.x += __shfl_xor(a3.x, 32, 64); a3.y += __shfl_xor(a3.y, 32, 64);

    if (g == 0) {
        uint4 wv;
        wv.x = ((unsigned)f2bf(fmaxf(asf(arow.x & 0xFFFF0000u) + a0.y, 0.f)) << 16)
             | f2bf(fmaxf(asf(arow.x << 16) + a0.x, 0.f));
        wv.y = ((unsigned)f2bf(fmaxf(asf(arow.y & 0xFFFF0000u) + a1.y, 0.f)) << 16)
             | f2bf(fmaxf(asf(arow.y << 16) + a1.x, 0.f));
        wv.z = ((unsigned)f2bf(fmaxf(asf(arow.z & 0xFFFF0000u) + a2.y, 0.f)) << 16)
             | f2bf(fmaxf(asf(arow.z << 16) + a2.x, 0.f));
        wv.w = ((unsigned)f2bf(fmaxf(asf(arow.w & 0xFFFF0000u) + a3.y, 0.f)) << 16)
             | f2bf(fmaxf(asf(arow.w << 16) + a3.x, 0.f));
        *(uint4*)(out + (size_t)node * 128 + f * 8) = wv;
    }
}

// ================= final GEMM + fused log_softmax (B in LDS, grid-stride) =================
__global__ __launch_bounds__(256) void gemm_final_ls(const unsigned short* __restrict__ x1bf,
                                                     const unsigned short* __restrict__ x2bf,
                                                     const unsigned short* __restrict__ Bsw,
                                                     const float* __restrict__ blin,
                                                     float* __restrict__ out, int N) {
    __shared__ unsigned short Bs[12288];  // 24 KB
    int t = threadIdx.x;
    {
        uint4* d4 = (uint4*)Bs;
        const uint4* s4 = (const uint4*)Bsw;
#pragma unroll
        for (int i = 0; i < 6; i++) d4[t + i * 256] = s4[t + i * 256];
    }
    __syncthreads();
    int w = t >> 6, L = t & 63;
    int cl = L & 15;
    float b0 = blin[cl], b1 = blin[16 + cl];
    float b2 = (cl < 8) ? blin[32 + cl] : 0.f;
    int nTiles = (N + 15) / 16;
    for (int tile = blockIdx.x * 4 + w; tile < nTiles; tile += gridDim.x * 4) {
        int r0 = tile * 16;
        int arow = r0 + (L & 15);
        f32x4 acc[3];
#pragma unroll
        for (int i = 0; i < 3; i++) acc[i] = (f32x4){0.f, 0.f, 0.f, 0.f};
#pragma unroll
        for (int kt = 0; kt < 8; kt++) {
            const unsigned short* Ab = (kt < 4) ? x1bf : x2bf;
            int kk = (kt & 3) * 32 + ((L >> 4) * 8);
            bf16x8 a = *((const bf16x8*)(Ab + (size_t)arow * 128 + kk));
#pragma unroll
            for (int ct = 0; ct < 3; ct++) {
                bf16x8 b = *(const bf16x8*)(Bs + (((kt * 3 + ct) * 64) + L) * 8);
                acc[ct] = __builtin_amdgcn_mfma_f32_16x16x32_bf16(a, b, acc[ct], 0, 0, 0);
            }
        }
        int rbase = r0 + (L >> 4) * 4;
#pragma unroll
        for (int r = 0; r < 4; r++) {
            int row = rbase + r;
            float v0 = acc[0][r] + b0;
            float v1 = acc[1][r] + b1;
            float v2 = (cl < 8) ? (acc[2][r] + b2) : -__builtin_inff();
            float m = fmaxf(fmaxf(v0, v1), v2);
#pragma unroll
            for (int off = 8; off >= 1; off >>= 1) m = fmaxf(m, __shfl_xor(m, off, 64));
            float e = __expf(v0 - m) + __expf(v1 - m) + ((cl < 8) ? __expf(v2 - m) : 0.f);
#pragma unroll
            for (int off = 8; off >= 1; off >>= 1) e += __shfl_xor(e, off, 64);
            float ls = m + __logf(e);
            float* op = out + (size_t)row * 40;
            op[cl] = v0 - ls;
            op[16 + cl] = v1 - ls;
            if (cl < 8) op[32 + cl] = v2 - ls;
        }
    }
}

extern "C" void kernel_launch(void* const* d_in, const int* in_sizes, int n_in,
                              void* d_out, int out_size, void* d_ws, size_t ws_size,
                              hipStream_t stream) {
    const float* x      = (const float*)d_in[0];
    const int*   edge   = (const int*)d_in[1];
    const float* Wrel1  = (const float*)d_in[2];
    const float* brel1  = (const float*)d_in[3];
    const float* Wroot1 = (const float*)d_in[4];
    const float* Wrel2  = (const float*)d_in[5];
    const float* brel2  = (const float*)d_in[6];
    const float* Wroot2 = (const float*)d_in[7];
    const float* Wlin   = (const float*)d_in[8];
    const float* blin   = (const float*)d_in[9];

    const int N = in_sizes[0] / 128;
    const int E = in_sizes[1] / 2;
    const int* src = edge;
    const int* dst = edge + E;

    const int nblk  = (E + EPB - 1) / EPB;                    // 391
    const int nbuck = (N + BUCKET_SIZE - 1) / BUCKET_SIZE;    // 391

    char* ws = (char*)d_ws;
    size_t off = 0;
    auto alloc = [&](size_t bytes) -> void* {
        void* p = ws + off;
        off += (bytes + 255) & ~(size_t)255;
        return p;
    };
    unsigned short* x1bf = (unsigned short*)alloc((size_t)N * 128 * 2);
    unsigned short* x2bf = (unsigned short*)alloc((size_t)N * 128 * 2);
    unsigned short* xr   = (unsigned short*)alloc((size_t)N * 128 * 2);
    unsigned short* accbf= (unsigned short*)alloc((size_t)N * 128 * 2);
    unsigned short* bsw1 = (unsigned short*)alloc(32768 * 2);
    unsigned short* bsw2 = (unsigned short*)alloc(32768 * 2);
    unsigned short* bswL = (unsigned short*)alloc(12288 * 2);
    int* ctrs       = (int*)alloc((size_t)(2 * nbuck) * 4);   // bucketTot | bucketCur
    int* bucketTot  = ctrs;
    int* bucketCur  = ctrs + nbuck;
    int* bucketBase = (int*)alloc((size_t)(nbuck + 1) * 4);
    int* part       = (int*)alloc((size_t)E * 4);
    int* csr_src    = (int*)alloc((size_t)E * 4);
    int* off_       = (int*)alloc((size_t)N * 4);
    int* deg_       = (int*)alloc((size_t)N * 4);

    const int rowTiles = (N + 15) / 16;
    const int gemmBlocks = (rowTiles + 3) / 4;
    const int nodeBlocks = (N + 3) / 4;

    // zero bucket counters (stream-ordered, capture-safe)
    hipMemsetAsync(ctrs, 0, (size_t)(2 * nbuck) * 4, stream);
    // K1: weight swizzles + per-chunk bucket counts
    prep<<<304 + nblk, 256, 0, stream>>>(Wrel1, Wroot1, Wrel2, Wroot2, Wlin, dst,
                                         bsw1, bsw2, bswL, bucketTot, E, nblk, nbuck);
    // K2: exclusive scan of bucket totals
    bucket_scan<<<1, 256, 0, stream>>>(bucketTot, bucketBase, nbuck);
    // K3: partition (atomic range-claim per chunk)
    edge_part<<<nblk, 256, 0, stream>>>(src, dst, bucketBase, bucketCur, part, E, nblk, nbuck);
    // K4: CSR finalize (391 blocks) + layer-1 GEMM (LDS-staged B) in one launch
    csrfin_gemm1<<<nbuck + gemmBlocks, 256, 0, stream>>>(part, bucketBase, off_, deg_, csr_src,
                                                         x, bsw1, brel1, xr, accbf, N, nbuck);
    // K5: layer-1 aggregation
    agg_relu_cvt<<<nodeBlocks, 256, 0, stream>>>(xr, accbf, off_, deg_, csr_src, x1bf, N);
    // K6: layer-2 GEMM (B in LDS, grid-stride)
    gemm_layer2<<<512, 256, 0, stream>>>(x1bf, bsw2, brel2, xr, accbf, N);
    // K7: layer-2 aggregation
    agg_relu_cvt<<<nodeBlocks, 256, 0, stream>>>(xr, accbf, off_, deg_, csr_src, x2bf, N);
    // K8: classifier + fused log_softmax (B in LDS, grid-stride)
    gemm_final_ls<<<512, 256, 0, stream>>>(x1bf, x2bf, bswL, blin, (float*)d_out, N);
}